// Round 9
// baseline (136.265 us; speedup 1.0000x reference)
//
#include <hip/hip_runtime.h>
#include <hip/hip_bf16.h>
#include <math.h>

#define Bn   4
#define CIN  128
#define Hh   64
#define Ww   64
#define HW   4096
#define CMID 64
#define KOC  100      // (scale*k_up)^2
#define H2   128
#define W2d  128
#define HW2  16384
#define KUP  5
#define BN_EPS 1e-5f

typedef __attribute__((ext_vector_type(8)))  short  short8v;
typedef __attribute__((ext_vector_type(16))) float  float16v;

__device__ __forceinline__ ushort f2bf(float v) {
    __hip_bfloat16 h = __float2bfloat16(v);
    return *(ushort*)&h;
}

// ---------------- Kernel A: 1x1 conv + BN + SiLU -> W1b NHWC bf16 [b][pix][64]
// thread = 2 px (float2) x 4 co. Piggyback: first 288 blocks build
// Abf[tap][kop 128][cm 64] bf16 (ko padded with 0).
__global__ __launch_bounds__(256) void comp_kernel(
    const float* __restrict__ X,
    const float* __restrict__ cw,
    const float* __restrict__ cg,
    const float* __restrict__ cb,
    const float* __restrict__ ew,
    unsigned* __restrict__ W1b,     // [b][pix][32] packed bf16 pairs
    ushort* __restrict__ Abf)       // [9][128][64]
{
    int tid = threadIdx.x;
    if (blockIdx.x < 288) {         // A-prep: 288*256 = 73728 = 9*128*64
        int i   = blockIdx.x * 256 + tid;
        int cm  = i & 63;
        int kop = (i >> 6) & 127;
        int tap = i >> 13;
        float v = (kop < KOC) ? ew[((size_t)(kop * CMID + cm)) * 9 + tap] : 0.f;
        Abf[i] = f2bf(v);
    }

    int gt  = blockIdx.x * 256 + tid;   // 512 blocks = 131072 threads
    int pg  = gt & 2047;                // 2048 pixel-pairs per b
    int cog = (gt >> 11) & 15;          // 16 groups of 4 co (block-uniform)
    int b   = gt >> 15;
    int pix = pg * 2;
    int co0 = cog * 4;

    const float* xb = X + (size_t)b * CIN * HW + pix;
    float acc[4][2];
#pragma unroll
    for (int g = 0; g < 4; ++g) { acc[g][0] = 0.f; acc[g][1] = 0.f; }

#pragma unroll 4
    for (int ci = 0; ci < CIN; ++ci) {
        float2 xv = *(const float2*)(xb + (size_t)ci * HW);
#pragma unroll
        for (int g = 0; g < 4; ++g) {
            float wv = cw[(size_t)(co0 + g) * CIN + ci];   // uniform -> s_load
            acc[g][0] += xv.x * wv;
            acc[g][1] += xv.y * wv;
        }
    }

    float inv_s = rsqrtf(1.0f + BN_EPS);
    ushort r[4][2];
#pragma unroll
    for (int g = 0; g < 4; ++g) {
        float s  = cg[co0 + g] * inv_s;
        float bb = cb[co0 + g];
#pragma unroll
        for (int i = 0; i < 2; ++i) {
            float v = acc[g][i] * s + bb;
            v = v / (1.f + expf(-v));   // SiLU
            r[g][i] = f2bf(v);
        }
    }
#pragma unroll
    for (int i = 0; i < 2; ++i) {
        unsigned lo = (unsigned)r[0][i] | ((unsigned)r[1][i] << 16);
        unsigned hi = (unsigned)r[2][i] | ((unsigned)r[3][i] << 16);
        unsigned* dst = W1b + ((size_t)b * HW + pix + i) * 32 + cog * 2;
        dst[0] = lo;
        dst[1] = hi;
    }
}

// ---------------- Kernel B: 3x3 conv as implicit GEMM via MFMA bf16
// C[100 pad 128][N=32 spatial] = sum_{tap,cmchunk} A x B(shifted W1 tile in LDS)
// block = (b, h, w-half); LDS tile: [3 rows][34 w][cm pad 72] bf16.
__global__ __launch_bounds__(256) void enc_kernel(
    const ushort* __restrict__ W1b_us,   // [b][pix][64] bf16
    const ushort* __restrict__ Abf,      // [9][128][64] bf16
    float* __restrict__ W2)              // [b][100][4096] fp32 (pre-BN logits)
{
    __shared__ ushort Bs[3 * 34 * 72];   // 14688 B

    int bid   = blockIdx.x;              // b*128 + h*2 + whalf -> 512 blocks
    int whalf = bid & 1;
    int h     = (bid >> 1) & 63;
    int b     = bid >> 7;
    int w0    = whalf * 32;
    int tid   = threadIdx.x;

    // stage B tile (bf16-pair granularity, coalesced in cm)
    const unsigned* src  = (const unsigned*)W1b_us;  // [b][pix][32]
    unsigned*       dstu = (unsigned*)Bs;            // w-slot stride 36 uints
    for (int i = tid; i < 3 * 34 * 32; i += 256) {
        int cp = i & 31;
        int t  = i >> 5;
        int wl = t % 34;
        int r  = t / 34;
        int gr = h - 1 + r, gw = w0 - 1 + wl;
        unsigned val = 0u;
        if ((unsigned)gr < 64u && (unsigned)gw < 64u)
            val = src[((size_t)b * HW + gr * 64 + gw) * 32 + cp];
        dstu[(r * 34 + wl) * 36 + cp] = val;
    }
    __syncthreads();

    int lane = tid & 63;
    int wid  = tid >> 6;                 // M-tile: ko base = wid*32
    int n    = lane & 31;
    int q    = lane >> 5;                // 0/1 -> k half

    float16v acc;
#pragma unroll
    for (int i = 0; i < 16; ++i) acc[i] = 0.f;

    const ushort* Arow = Abf + ((size_t)(wid * 32 + n)) * 64 + q * 8;

#pragma unroll
    for (int tap = 0; tap < 9; ++tap) {
        int dy = tap / 3, dx = tap % 3;
        int bbase = ((dy * 34) + n + dx) * 72 + q * 8;     // ushort idx, 16B aligned
        const ushort* Atap = Arow + (size_t)tap * 128 * 64;
#pragma unroll
        for (int c = 0; c < 4; ++c) {
            short8v a = *(const short8v*)(Atap + c * 16);
            short8v bf = *(const short8v*)(Bs + bbase + c * 16);
            acc = __builtin_amdgcn_mfma_f32_32x32x16_bf16(a, bf, acc, 0, 0, 0);
        }
    }

    // store: col = lane&31 = n (pixel), row = (reg&3)+8*(reg>>2)+4*q = ko offset
    int pixn = h * 64 + w0 + n;
    float* Wp = W2 + (size_t)b * KOC * HW + pixn;
#pragma unroll
    for (int reg = 0; reg < 16; ++reg) {
        int row = (reg & 3) + 8 * (reg >> 2) + 4 * q;
        int ko  = wid * 32 + row;
        if (ko < KOC) Wp[(size_t)ko * HW] = acc[reg];
    }
}

// ---------------- Kernel C+D fused: BN + softmax (LDS) + CARAFE reassembly
// block = (b, h, 32-px half-row). Phase 1: 128 threads compute softmax for
// (px, sub) into LDS. Phase 2: 256 threads = 32 px x 8 channel-groups; each
// caches its px's 100 weights in VGPRs, loops 16 channels:
// 25 coalesced X loads -> 4 outputs (100 FMA).
// (parity fold: floor((h2-4+2*ki)/2) = h + ki - 2 for both parities of h2)
__global__ __launch_bounds__(256) void carafe_kernel(
    const float* __restrict__ X,
    const float* __restrict__ W2,
    const float* __restrict__ eg,
    const float* __restrict__ eb,
    float* __restrict__ out)
{
    __shared__ float wsm[4][25][32];     // 12.8 KB

    int bid   = blockIdx.x;              // b*128 + h*2 + whalf -> 512 blocks
    int whalf = bid & 1;
    int h     = (bid >> 1) & 63;
    int b     = bid >> 7;
    int w0    = whalf * 32;
    int tid   = threadIdx.x;

    if (tid < 128) {
        int px  = tid & 31;
        int sub = tid >> 5;
        float inv_s = rsqrtf(1.0f + BN_EPS);
        const float* pi = W2 + (size_t)b * KOC * HW + h * 64 + w0 + px;
        float v[25];
        float m = -1e30f;
#pragma unroll
        for (int k = 0; k < 25; ++k) {
            int ko = 4 * k + sub;
            v[k] = pi[(size_t)ko * HW] * (eg[ko] * inv_s) + eb[ko];
            m = fmaxf(m, v[k]);
        }
        float sum = 0.f;
#pragma unroll
        for (int k = 0; k < 25; ++k) {
            v[k] = expf(v[k] - m);
            sum += v[k];
        }
        float inv = 1.f / sum;
#pragma unroll
        for (int k = 0; k < 25; ++k)
            wsm[sub][k][px] = v[k] * inv;
    }
    __syncthreads();

    int px  = tid & 31;
    int grp = tid >> 5;                  // 8 groups of 16 channels
    int w   = w0 + px;
    int c0  = grp * 16;

    float wt[100];
#pragma unroll
    for (int sub = 0; sub < 4; ++sub)
#pragma unroll
        for (int k = 0; k < 25; ++k)
            wt[sub * 25 + k] = wsm[sub][k][px];

    int off[25];
#pragma unroll
    for (int ki = 0; ki < 5; ++ki) {
#pragma unroll
        for (int kj = 0; kj < 5; ++kj) {
            int k = ki * 5 + kj;
            int r = h + ki - 2, cc = w + kj - 2;
            bool valid = ((unsigned)r < 64u) && ((unsigned)cc < 64u);
            int rc = r < 0 ? 0 : (r > 63 ? 63 : r);
            int cx = cc < 0 ? 0 : (cc > 63 ? 63 : cc);
            off[k] = rc * Ww + cx;
            if (!valid) { wt[k] = 0.f; wt[25+k] = 0.f; wt[50+k] = 0.f; wt[75+k] = 0.f; }
        }
    }

    const float* xp = X + ((size_t)b * CIN + c0) * HW;
    float* o0 = out + ((size_t)b * CIN + c0) * HW2 + (2 * h) * W2d + 2 * w;

    for (int c = 0; c < 16; ++c) {
        float x[25];
#pragma unroll
        for (int k = 0; k < 25; ++k) x[k] = xp[off[k]];
        float a0 = 0.f, a1 = 0.f, a2 = 0.f, a3 = 0.f;
#pragma unroll
        for (int k = 0; k < 25; ++k) {
            float xv = x[k];
            a0 += wt[k]      * xv;
            a1 += wt[25 + k] * xv;
            a2 += wt[50 + k] * xv;
            a3 += wt[75 + k] * xv;
        }
        *(float2*)o0          = make_float2(a0, a1);
        *(float2*)(o0 + W2d)  = make_float2(a2, a3);
        xp += HW;
        o0 += HW2;
    }
}

extern "C" void kernel_launch(void* const* d_in, const int* in_sizes, int n_in,
                              void* d_out, int out_size, void* d_ws, size_t ws_size,
                              hipStream_t stream)
{
    const float* X  = (const float*)d_in[0];
    const float* cw = (const float*)d_in[1];
    const float* cg = (const float*)d_in[2];
    const float* cb = (const float*)d_in[3];
    const float* ew = (const float*)d_in[4];
    const float* eg = (const float*)d_in[5];
    const float* eb = (const float*)d_in[6];
    float* out = (float*)d_out;

    char* ws = (char*)d_ws;
    unsigned* W1b = (unsigned*)ws;                        // 4*4096*32 u32 = 2 MB
    ushort*   Abf = (ushort*)(ws + 2097152);              // 9*128*64 = 147456 B
    float*    W2  = (float*)(ws + 2097152 + 147456);      // 6.55 MB

    comp_kernel  <<<512, 256, 0, stream>>>(X, cw, cg, cb, ew, W1b, Abf);
    enc_kernel   <<<512, 256, 0, stream>>>((const ushort*)W1b, Abf, W2);
    carafe_kernel<<<512, 256, 0, stream>>>(X, W2, eg, eb, out);
}